// Round 1
// baseline (122.712 us; speedup 1.0000x reference)
//
#include <hip/hip_runtime.h>
#include <cstdint>
#include <cstddef>

// Problem constants
#define NB    64        // batch
#define NPAT  196       // patches per image
#define MTOT  (NB*NPAT) // 12544 GEMM rows
#define KTOT  768
#define NTOT  768

typedef float  f32x4  __attribute__((ext_vector_type(4)));
typedef __bf16 bf16x8 __attribute__((ext_vector_type(8)));

// ---------------- Prepass: patchify + fp32->bf16 convert + cls rows ----------------
// A-part: MTOT*KTOT/8 = 1,204,224 chunks of 8 -> 4704 blocks of 256
// W-part: 768*768/8  = 73,728 chunks         -> 288 blocks
// cls:    64*768/4   = 12,288 float4 chunks  -> 48 blocks
#define A_BLOCKS   4704
#define W_BLOCKS   288
#define CLS_BLOCKS 48

__global__ __launch_bounds__(256) void prep_kernel(
    const float* __restrict__ images, const float* __restrict__ Wm,
    const float* __restrict__ cls, float* __restrict__ out,
    __bf16* __restrict__ Abuf, __bf16* __restrict__ Wbuf) {
  const int bid = blockIdx.x;
  const int tid = threadIdx.x;
  if (bid < A_BLOCKS) {
    const int q  = bid * 256 + tid;        // chunk of 8 k-elems
    const int m  = q / 96;                 // 96 chunks per row (K=768)
    const int kc = q - m * 96;
    const int bb = m / 196;
    const int p  = m - bb * 196;
    const int pi = p / 14;
    const int pj = p - pi * 14;
    const int c   = kc >> 5;               // d0 = kc*8; c = d0/256
    const int ph  = (kc & 31) >> 1;        // (d0%256)/16
    const int pw0 = (kc & 1) << 3;         // d0%16 in {0,8}
    const size_t src =
        ((size_t)((bb * 3 + c) * 224 + pi * 16 + ph)) * 224 + (size_t)(pj * 16 + pw0);
    const float4 v0 = *(const float4*)(images + src);
    const float4 v1 = *(const float4*)(images + src + 4);
    bf16x8 o;
    o[0] = (__bf16)v0.x; o[1] = (__bf16)v0.y; o[2] = (__bf16)v0.z; o[3] = (__bf16)v0.w;
    o[4] = (__bf16)v1.x; o[5] = (__bf16)v1.y; o[6] = (__bf16)v1.z; o[7] = (__bf16)v1.w;
    *(bf16x8*)(Abuf + (size_t)q * 8) = o;
  } else if (bid < A_BLOCKS + W_BLOCKS) {
    const int q = (bid - A_BLOCKS) * 256 + tid;
    const float4 v0 = *(const float4*)(Wm + (size_t)q * 8);
    const float4 v1 = *(const float4*)(Wm + (size_t)q * 8 + 4);
    bf16x8 o;
    o[0] = (__bf16)v0.x; o[1] = (__bf16)v0.y; o[2] = (__bf16)v0.z; o[3] = (__bf16)v0.w;
    o[4] = (__bf16)v1.x; o[5] = (__bf16)v1.y; o[6] = (__bf16)v1.z; o[7] = (__bf16)v1.w;
    *(bf16x8*)(Wbuf + (size_t)q * 8) = o;
  } else {
    const int t  = (bid - A_BLOCKS - W_BLOCKS) * 256 + tid;  // float4 chunk
    const int bb = t / 192;                                  // 192 chunks per row
    const int r  = t - bb * 192;
    const float4 v = *(const float4*)(cls + r * 4);
    *(float4*)(out + (size_t)bb * 197 * 768 + r * 4) = v;    // token 0 = class token
  }
}

// ---------------- GEMM: C[m,h] = sum_k A[m,k]*W[h,k] + b[h], scattered to out ----------------
// 128x128 tile, BK=32, 256 threads = 4 waves (2x2 of 64x64), 16x16x32 bf16 MFMA.
#define BM 128
#define BN 128
#define BK 32
#define NBLK_N 6   // 768/128

__device__ __forceinline__ void gload_lds16(const void* g, void* l) {
  __builtin_amdgcn_global_load_lds((__attribute__((address_space(1))) void*)(g),
                                   (__attribute__((address_space(3))) void*)(l),
                                   16, 0, 0);
}

__global__ __launch_bounds__(256) void gemm_kernel(
    const __bf16* __restrict__ A, const __bf16* __restrict__ Wb,
    const float* __restrict__ bias, float* __restrict__ out) {
  __shared__ __bf16 As[BM * BK];  // 8 KB, row-major [128][32]
  __shared__ __bf16 Bs[BN * BK];  // 8 KB, row-major [128][32]

  const int tid  = threadIdx.x;
  const int bx   = blockIdx.x;
  const int nblk = bx % NBLK_N;
  const int mblk = bx / NBLK_N;
  const int m0 = mblk * BM;
  const int n0 = nblk * BN;
  const int wave = tid >> 6;
  const int lane = tid & 63;
  const int wm = (wave & 1) * 64;   // wave sub-tile origin in M
  const int wn = (wave >> 1) * 64;  // in N
  const int lrow = lane & 15;
  const int lq   = lane >> 4;

  f32x4 acc[4][4] = {};

  // staging: 512 16B chunks per tile; thread handles chunks q0=tid, q1=tid+256
  const int q0 = tid, q1 = tid + 256;
  const __bf16* pA0 = A  + (size_t)(m0 + (q0 >> 2)) * KTOT + (q0 & 3) * 8;
  const __bf16* pA1 = A  + (size_t)(m0 + (q1 >> 2)) * KTOT + (q1 & 3) * 8;
  const __bf16* pB0 = Wb + (size_t)(n0 + (q0 >> 2)) * KTOT + (q0 & 3) * 8;
  const __bf16* pB1 = Wb + (size_t)(n0 + (q1 >> 2)) * KTOT + (q1 & 3) * 8;
  __bf16* lA0 = &As[wave * 512];          // + lane*16B implicit (wave-uniform base)
  __bf16* lA1 = &As[2048 + wave * 512];
  __bf16* lB0 = &Bs[wave * 512];
  __bf16* lB1 = &Bs[2048 + wave * 512];

  for (int kt = 0; kt < KTOT / BK; ++kt) {
    gload_lds16(pA0, lA0);
    gload_lds16(pA1, lA1);
    gload_lds16(pB0, lB0);
    gload_lds16(pB1, lB1);
    pA0 += BK; pA1 += BK; pB0 += BK; pB1 += BK;
    __syncthreads();  // drains vmcnt -> LDS tiles complete

    bf16x8 af[4], bf[4];
#pragma unroll
    for (int i = 0; i < 4; ++i)
      af[i] = *(const bf16x8*)&As[(wm + i * 16 + lrow) * BK + lq * 8];
#pragma unroll
    for (int j = 0; j < 4; ++j)
      bf[j] = *(const bf16x8*)&Bs[(wn + j * 16 + lrow) * BK + lq * 8];

#pragma unroll
    for (int i = 0; i < 4; ++i)
#pragma unroll
      for (int j = 0; j < 4; ++j)
        acc[i][j] = __builtin_amdgcn_mfma_f32_16x16x32_bf16(af[i], bf[j], acc[i][j], 0, 0, 0);

    __syncthreads();  // protect LDS before next stage
  }

  // Epilogue: C/D layout col=lane&15, row=(lane>>4)*4+r. Scatter to out[(bb*197+1+p)*768+h].
#pragma unroll
  for (int j = 0; j < 4; ++j) {
    const int h  = n0 + wn + j * 16 + lrow;
    const float bv = bias[h];
#pragma unroll
    for (int i = 0; i < 4; ++i) {
      const int mbase = m0 + wm + i * 16 + lq * 4;
#pragma unroll
      for (int r = 0; r < 4; ++r) {
        const int m  = mbase + r;
        const int bb = m / 196;
        const int p  = m - bb * 196;
        out[(size_t)(bb * 197 + 1 + p) * 768 + h] = acc[i][j][r] + bv;
      }
    }
  }
}

extern "C" void kernel_launch(void* const* d_in, const int* in_sizes, int n_in,
                              void* d_out, int out_size, void* d_ws, size_t ws_size,
                              hipStream_t stream) {
  const float* images = (const float*)d_in[0];  // [64,3,224,224]
  const float* Wm     = (const float*)d_in[1];  // [768,768]
  const float* b      = (const float*)d_in[2];  // [768]
  const float* cls    = (const float*)d_in[3];  // [1,768]
  float* out = (float*)d_out;                   // [64,197,768]

  __bf16* Abuf = (__bf16*)d_ws;                 // 12544*768 bf16 = 19.27 MB
  __bf16* Wbuf = Abuf + (size_t)MTOT * KTOT;    // 768*768 bf16 = 1.18 MB
  (void)in_sizes; (void)n_in; (void)out_size; (void)ws_size;

  prep_kernel<<<A_BLOCKS + W_BLOCKS + CLS_BLOCKS, 256, 0, stream>>>(
      images, Wm, cls, out, Abuf, Wbuf);
  gemm_kernel<<<(MTOT / BM) * NBLK_N, 256, 0, stream>>>(Abuf, Wbuf, b, out);
}

// Round 2
// 118.321 us; speedup vs baseline: 1.0371x; 1.0371x over previous
//
#include <hip/hip_runtime.h>
#include <cstdint>
#include <cstddef>

// Problem: out[64,197,768] = concat(cls, patchify(images[64,3,224,224]) @ W^T + b)
#define MTOT 12544   // 64*196 GEMM rows
#define KTOT 768
#define NTOT 768

typedef float  f32x4  __attribute__((ext_vector_type(4)));
typedef __bf16 bf16x8 __attribute__((ext_vector_type(8)));

// ---------------- Prep: coalesced fp32->bf16 convert (images, W) + cls rows ----------------
#define IMG_ELEMS (64*3*224*224)       // 9,633,792
#define W_ELEMS   (768*768)            // 589,824
#define A_BLOCKS  (IMG_ELEMS/8/256)    // 4704
#define W_BLOCKS  (W_ELEMS/8/256)      // 288
#define CLS_BLOCKS 48                  // 64*768 floats / 4 / 256

__global__ __launch_bounds__(256) void prep_kernel(
    const float* __restrict__ images, const float* __restrict__ Wm,
    const float* __restrict__ cls, float* __restrict__ out,
    __bf16* __restrict__ imgb, __bf16* __restrict__ Wb) {
  const int bid = blockIdx.x, tid = threadIdx.x;
  if (bid < A_BLOCKS) {
    const size_t q = (size_t)bid * 256 + tid;
    const float4 v0 = *(const float4*)(images + q * 8);
    const float4 v1 = *(const float4*)(images + q * 8 + 4);
    bf16x8 o;
    o[0]=(__bf16)v0.x; o[1]=(__bf16)v0.y; o[2]=(__bf16)v0.z; o[3]=(__bf16)v0.w;
    o[4]=(__bf16)v1.x; o[5]=(__bf16)v1.y; o[6]=(__bf16)v1.z; o[7]=(__bf16)v1.w;
    *(bf16x8*)(imgb + q * 8) = o;
  } else if (bid < A_BLOCKS + W_BLOCKS) {
    const size_t q = (size_t)(bid - A_BLOCKS) * 256 + tid;
    const float4 v0 = *(const float4*)(Wm + q * 8);
    const float4 v1 = *(const float4*)(Wm + q * 8 + 4);
    bf16x8 o;
    o[0]=(__bf16)v0.x; o[1]=(__bf16)v0.y; o[2]=(__bf16)v0.z; o[3]=(__bf16)v0.w;
    o[4]=(__bf16)v1.x; o[5]=(__bf16)v1.y; o[6]=(__bf16)v1.z; o[7]=(__bf16)v1.w;
    *(bf16x8*)(Wb + q * 8) = o;
  } else {
    const int t  = (bid - A_BLOCKS - W_BLOCKS) * 256 + tid;
    const int bb = t / 192;             // 192 float4 per row
    const int r  = t - bb * 192;
    *(float4*)(out + (size_t)bb * 197 * 768 + r * 4) = *(const float4*)(cls + r * 4);
  }
}

// ---------------- GEMM: fused patchify-gather + MFMA ----------------
// BM=64, BN=128, BK=64 -> grid 196*6 = 1176 blocks (4.6/CU).
// LDS layout [kstep][row][32] keeps 64B row stride (conflict-optimal b128 reads).
#define BM 64
#define BN 128
#define BK 64
#define NBLK_N 6   // 768/128

__device__ __forceinline__ void gload_lds16(const void* g, void* l) {
  __builtin_amdgcn_global_load_lds((__attribute__((address_space(1))) void*)(g),
                                   (__attribute__((address_space(3))) void*)(l),
                                   16, 0, 0);
}

__global__ __launch_bounds__(256) void gemm_kernel(
    const __bf16* __restrict__ imgb, const __bf16* __restrict__ Wb,
    const float* __restrict__ bias, float* __restrict__ out) {
  __shared__ __bf16 As[2 * 64 * 32];   // 8 KB: [kstep][row 0..63][k 0..31]
  __shared__ __bf16 Bs[2 * 128 * 32];  // 16 KB

  const int tid  = threadIdx.x;
  const int bx   = blockIdx.x;
  const int mblk = bx / NBLK_N;
  const int nblk = bx - mblk * NBLK_N;
  const int m0 = mblk * BM;
  const int n0 = nblk * BN;
  const int wave = tid >> 6, lane = tid & 63;
  const int wm = (wave & 1) * 32;   // wave sub-tile 32(M) x 64(N)
  const int wn = (wave >> 1) * 64;
  const int lrow = lane & 15, lq = lane >> 4;

  f32x4 acc[2][4] = {};

  // A staging: 512 16B chunks; chunk c = wave*128 + s*64 + lane
  //   kstep=c>>8, row=(c&255)>>2, jc=c&3 -> k_in_tile = kstep*32+jc*8
  //   global: patchify gather; per-kt advance is a wave-uniform elem delta.
  const __bf16* pA[2];
#pragma unroll
  for (int s = 0; s < 2; ++s) {
    const int c = wave * 128 + s * 64 + lane;
    const int kstep = c >> 8, rem = c & 255;
    const int row = rem >> 2, jc = rem & 3;
    const int m = m0 + row;
    const int bb = m / 196, p = m - bb * 196;
    const int pi = p / 14, pj = p - pi * 14;
    const int ph_off = kstep * 2 + (jc >> 1);
    const int pw_off = (jc & 1) * 8;
    const size_t e = ((size_t)(bb * 3 * 224 + pi * 16 + ph_off)) * 224 + pj * 16 + pw_off;
    pA[s] = imgb + e;
  }
  // B staging: 1024 chunks; c = wave*256 + s*64 + lane
  const __bf16* pB[4];
#pragma unroll
  for (int s = 0; s < 4; ++s) {
    const int c = wave * 256 + s * 64 + lane;
    const int kstep = c >> 9, rem = c & 511;
    const int h = rem >> 2, jc = rem & 3;
    pB[s] = Wb + (size_t)(n0 + h) * 768 + kstep * 32 + jc * 8;
  }
  __bf16* lA[2];
  __bf16* lB[4];
#pragma unroll
  for (int s = 0; s < 2; ++s) lA[s] = As + (wave * 128 + s * 64) * 8;  // chunk*8 elems
#pragma unroll
  for (int s = 0; s < 4; ++s) lB[s] = Bs + (wave * 256 + s * 64) * 8;

  for (int kt = 0; kt < KTOT / BK; ++kt) {   // 12 iterations
#pragma unroll
    for (int s = 0; s < 2; ++s) gload_lds16(pA[s], lA[s]);
#pragma unroll
    for (int s = 0; s < 4; ++s) gload_lds16(pB[s], lB[s]);
    // advance: +4 image rows within channel; at channel crossing +50176-2688 elems
    const int dA = ((kt & 3) == 3) ? 47488 : 896;
    pA[0] += dA; pA[1] += dA;
    pB[0] += BK; pB[1] += BK; pB[2] += BK; pB[3] += BK;
    __syncthreads();   // drain vmcnt -> tiles complete

#pragma unroll
    for (int ks = 0; ks < 2; ++ks) {
      bf16x8 af[2], bf[4];
#pragma unroll
      for (int i = 0; i < 2; ++i)
        af[i] = *(const bf16x8*)&As[ks * 2048 + (wm + i * 16 + lrow) * 32 + lq * 8];
#pragma unroll
      for (int j = 0; j < 4; ++j)
        bf[j] = *(const bf16x8*)&Bs[ks * 4096 + (wn + j * 16 + lrow) * 32 + lq * 8];
#pragma unroll
      for (int i = 0; i < 2; ++i)
#pragma unroll
        for (int j = 0; j < 4; ++j)
          acc[i][j] = __builtin_amdgcn_mfma_f32_16x16x32_bf16(af[i], bf[j], acc[i][j], 0, 0, 0);
    }
    __syncthreads();
  }

  // Epilogue: C/D layout col=lane&15, row=(lane>>4)*4+r (round-1-verified convention)
#pragma unroll
  for (int j = 0; j < 4; ++j) {
    const int h  = n0 + wn + j * 16 + lrow;
    const float bv = bias[h];
#pragma unroll
    for (int i = 0; i < 2; ++i) {
      const int mb = m0 + wm + i * 16 + lq * 4;
#pragma unroll
      for (int r = 0; r < 4; ++r) {
        const int m  = mb + r;
        const int bb = m / 196, p = m - bb * 196;
        out[(size_t)(bb * 197 + 1 + p) * 768 + h] = acc[i][j][r] + bv;
      }
    }
  }
}

extern "C" void kernel_launch(void* const* d_in, const int* in_sizes, int n_in,
                              void* d_out, int out_size, void* d_ws, size_t ws_size,
                              hipStream_t stream) {
  const float* images = (const float*)d_in[0];  // [64,3,224,224]
  const float* Wm     = (const float*)d_in[1];  // [768,768]
  const float* b      = (const float*)d_in[2];  // [768]
  const float* cls    = (const float*)d_in[3];  // [1,768]
  float* out = (float*)d_out;                   // [64,197,768]

  __bf16* imgb = (__bf16*)d_ws;                   // 19.27 MB
  __bf16* Wb   = imgb + (size_t)IMG_ELEMS;        // 1.18 MB
  (void)in_sizes; (void)n_in; (void)out_size; (void)ws_size;

  prep_kernel<<<A_BLOCKS + W_BLOCKS + CLS_BLOCKS, 256, 0, stream>>>(
      images, Wm, cls, out, imgb, Wb);
  gemm_kernel<<<(MTOT / BM) * NBLK_N, 256, 0, stream>>>(imgb, Wb, b, out);
}